// Round 12
// baseline (140.974 us; speedup 1.0000x reference)
//
#include <hip/hip_runtime.h>
#include <hip/hip_bf16.h>

#define LSEQ 2048
#define DM   1024
#define NH   16

typedef __attribute__((ext_vector_type(8)))  short bf16x8;
typedef __attribute__((ext_vector_type(8)))  unsigned short u16x8;
typedef __attribute__((ext_vector_type(4)))  float f32x4;
typedef __attribute__((ext_vector_type(16))) float f32x16;
typedef __attribute__((ext_vector_type(4)))  unsigned int u32x4;

#define LOG2E 1.4426950408889634f
#define C1SC  0.18033688011112042f   /* 0.125 * log2(e) */

static __device__ __forceinline__ float exp2fast(float x) {
  return __builtin_amdgcn_exp2f(x);
}

static __device__ __forceinline__ unsigned short f2bf(float f) {
  unsigned int u = __float_as_uint(f);
  u += 0x7FFFu + ((u >> 16) & 1u);
  return (unsigned short)(u >> 16);
}

static __device__ __forceinline__ unsigned pk2(float a, float b) {
  __hip_bfloat162 t = __float22bfloat162_rn(make_float2(a, b));
  return *reinterpret_cast<unsigned*>(&t);
}

// unpack 16 packed bf16 (two 16B vectors) -> f32x16
static __device__ __forceinline__ f32x16 unpack16(u16x8 a, u16x8 b) {
  const u32x4 ua = __builtin_bit_cast(u32x4, a);
  const u32x4 ub = __builtin_bit_cast(u32x4, b);
  f32x16 r;
#pragma unroll
  for (int i = 0; i < 4; ++i) {
    r[2 * i]     = __uint_as_float(ua[i] << 16);
    r[2 * i + 1] = __uint_as_float(ua[i] & 0xFFFF0000u);
    r[8 + 2 * i]     = __uint_as_float(ub[i] << 16);
    r[8 + 2 * i + 1] = __uint_as_float(ub[i] & 0xFFFF0000u);
  }
  return r;
}

// pack 8 floats (natural order) -> PV B-fragment (V is k-permuted to match)
static __device__ __forceinline__ bf16x8 pack8(const f32x16& s, int base) {
  u32x4 w;
  w[0] = pk2(s[base + 0], s[base + 1]); w[1] = pk2(s[base + 2], s[base + 3]);
  w[2] = pk2(s[base + 4], s[base + 5]); w[3] = pk2(s[base + 6], s[base + 7]);
  return __builtin_bit_cast(bf16x8, w);
}

static __device__ __forceinline__ void gld_lds16(const unsigned short* g, unsigned short* l) {
  __builtin_amdgcn_global_load_lds(
      (const __attribute__((address_space(1))) unsigned int*)g,
      (__attribute__((address_space(3))) unsigned int*)l, 16, 0, 0);
}

// ---------------- data fp32 -> bf16 ----------------
__global__ void k_convert_data(const float* __restrict__ src,
                               unsigned short* __restrict__ dst, int n4) {
  int i = blockIdx.x * 256 + threadIdx.x;
  if (i >= n4) return;
  float4 v = reinterpret_cast<const float4*>(src)[i];
  ushort4 o;
  o.x = f2bf(v.x); o.y = f2bf(v.y); o.z = f2bf(v.z); o.w = f2bf(v.w);
  reinterpret_cast<ushort4*>(dst)[i] = o;
}

// ---------------- W -> Wt bf16 (transpose to [n][k]) ----------------
__global__ void k_transpose_w(const float* __restrict__ Wq,
                              const float* __restrict__ Wk,
                              const float* __restrict__ Wv,
                              unsigned short* __restrict__ Wt) {
  __shared__ unsigned short tile[64][65];
  const float* W = (blockIdx.z == 0) ? Wq : (blockIdx.z == 1) ? Wk : Wv;
  int n0 = blockIdx.x * 64, k0 = blockIdx.y * 64;
  int t = threadIdx.x;
  int c = t & 63, r0 = t >> 6;
  for (int i = 0; i < 16; ++i) {
    int r = r0 + i * 4;
    tile[r][c] = f2bf(W[(size_t)(k0 + r) * DM + n0 + c]);
  }
  __syncthreads();
  size_t nbase = (size_t)blockIdx.z * DM + n0;
  for (int i = 0; i < 16; ++i) {
    int n = r0 + i * 4;
    Wt[(nbase + n) * DM + k0 + c] = tile[c][n];
  }
}

// ---------------- mask -> maskCb (MFMA C-layout bf16, *log2e) + zero-tile flags ----------------
__global__ void k_maskC(const float* __restrict__ mask,
                        unsigned short* __restrict__ maskCb,
                        int* __restrict__ zflags) {
  __shared__ float tile[64][65];
  __shared__ int nz;
  int q0 = blockIdx.x * 64, kv0 = blockIdx.y * 64;
  int t = threadIdx.x;
  if (t == 0) nz = 0;
  __syncthreads();
  int c = t & 63, r0 = t >> 6;
  int lnz = 0;
  for (int i = 0; i < 16; ++i) {
    int r = r0 + i * 4;
    float v = mask[(size_t)(q0 + r) * LSEQ + kv0 + c];
    tile[r][c] = v;
    lnz |= (v != 0.0f);
  }
  if (lnz) atomicOr(&nz, 1);
  __syncthreads();
  const int q = t & 63, slot = t >> 6;         // slot = tt*2 + hh
  const int tt = slot >> 1, hh = slot & 1;
  u16x8 va, vb;
#pragma unroll
  for (int r = 0; r < 8; ++r) {
    const int kvloc = 32 * tt + 4 * hh + (r & 3) + 8 * (r >> 2);
    va[r] = f2bf(tile[q][kvloc] * LOG2E);
  }
#pragma unroll
  for (int r = 8; r < 16; ++r) {
    const int kvloc = 32 * tt + 4 * hh + (r & 3) + 8 * (r >> 2);
    vb[r - 8] = f2bf(tile[q][kvloc] * LOG2E);
  }
  unsigned short* dst = maskCb + ((size_t)((kv0 >> 6) * 4 + slot) * 2048 + q0 + q) * 16;
  *reinterpret_cast<u16x8*>(dst) = va;
  *reinterpret_cast<u16x8*>(dst + 8) = vb;
  if (t == 0) zflags[blockIdx.y * 32 + blockIdx.x] = (nz == 0);
}

// ---------------- fused QKV GEMM + bias + rotary (+Q pre-scale) + attn-tiled layouts ----------------
__global__ __launch_bounds__(256) void k_qkv_gemm(
    const unsigned short* __restrict__ A, const unsigned short* __restrict__ Bt,
    const float* __restrict__ bq, const float* __restrict__ bk,
    const float* __restrict__ bv, const float* __restrict__ temporal,
    unsigned short* __restrict__ qbuf, unsigned short* __restrict__ kbuf,
    unsigned short* __restrict__ vtbuf) {
  __shared__ unsigned short As[128 * 32];
  __shared__ unsigned short Bs[128 * 32];
  __shared__ unsigned short otile[128 * 136];
  const int tid = threadIdx.x;
  const int lane = tid & 63, wid = tid >> 6;
  const int wm = wid >> 1, wn = wid & 1;
  const int lr = lane & 15, lg = lane >> 4;

  const int bid = blockIdx.x;
  const int xcd = bid & 7, rr = bid >> 3;
  const int mblk = xcd * 4 + (rr / 24);
  const int nblk = rr % 24;
  const int m0 = mblk * 128;
  const int n0 = nblk * 128;

  f32x4 acc[4][4] = {};

  const int e0 = tid * 8;
  const int e1 = (256 + tid) * 8;
  const int ra0 = e0 >> 5, ca0 = e0 & 31;
  const int ra1 = e1 >> 5, ca1 = e1 & 31;
  unsigned short* lA0 = As + wid * 512;
  unsigned short* lA1 = As + 2048 + wid * 512;
  unsigned short* lB0 = Bs + wid * 512;
  unsigned short* lB1 = Bs + 2048 + wid * 512;

  for (int k0 = 0; k0 < DM; k0 += 32) {
    __syncthreads();
    gld_lds16(A + (size_t)(m0 + ra0) * DM + k0 + ca0, lA0);
    gld_lds16(A + (size_t)(m0 + ra1) * DM + k0 + ca1, lA1);
    gld_lds16(Bt + (size_t)(n0 + ra0) * DM + k0 + ca0, lB0);
    gld_lds16(Bt + (size_t)(n0 + ra1) * DM + k0 + ca1, lB1);
    __syncthreads();
    bf16x8 af[4], bfv[4];
    for (int mi = 0; mi < 4; ++mi)
      af[mi] = *reinterpret_cast<const bf16x8*>(As + (wm * 64 + mi * 16 + lr) * 32 + lg * 8);
    for (int ni = 0; ni < 4; ++ni)
      bfv[ni] = *reinterpret_cast<const bf16x8*>(Bs + (wn * 64 + ni * 16 + lr) * 32 + lg * 8);
    for (int mi = 0; mi < 4; ++mi)
      for (int ni = 0; ni < 4; ++ni)
        acc[mi][ni] = __builtin_amdgcn_mfma_f32_16x16x32_bf16(af[mi], bfv[ni], acc[mi][ni], 0, 0, 0);
  }

  const int mat = n0 >> 10;
  const int c0 = n0 & 1023;
  const int bb = m0 >> 11;
  const int mloc = m0 & 2047;
  const float qscale = (mat == 0) ? C1SC : 1.f;

  for (int mi = 0; mi < 4; ++mi) {
    const int rrel_base = wm * 64 + mi * 16 + lg * 4;
    for (int ni = 0; ni < 4; ++ni) {
      const int crel = wn * 64 + ni * 16 + lr;
      const int c = (c0 + crel);
      const int d = c & 63;
      const float bias = (mat == 0 ? bq : mat == 1 ? bk : bv)[c];
      f32x4 v = acc[mi][ni];
      if (mat < 2) {
        const int jj = d & 15, tt = d >> 4;
        const float fr = __expf(-(float)(jj & 14) * 0.5756462732485115f);
        const float sign = (d & 1) ? 1.f : -1.f;
        for (int j = 0; j < 4; ++j) {
          const int rrel = rrel_base + j;
          const float x = v[j] + bias;
          const float part = __shfl_xor(x, 1, 64);
          const int lqs = mloc + rrel;
          const float fq = temporal[((size_t)bb * LSEQ + lqs) * 4 + tt] * fr;
          float sn, cs;
          __sincosf(fq, &sn, &cs);
          otile[rrel * 136 + crel] = f2bf((x * cs + sign * part * sn) * qscale);
        }
      } else {
        for (int j = 0; j < 4; ++j) {
          const int rrel = rrel_base + j;
          otile[crel * 136 + rrel] = f2bf(v[j] + bias);
        }
      }
    }
  }
  __syncthreads();

  for (int i = 0; i < 2; ++i) {
    const int h = (c0 >> 6) + i;
    const size_t bh = (size_t)(bb * NH + h);
    if (mat == 0) {
      const size_t base = (bh * LSEQ + mloc) * 64;
#pragma unroll
      for (int kk2 = 0; kk2 < 4; ++kk2) {
        const int e = kk2 * 2048 + tid * 8;
        const int r = e >> 6, d = e & 63;
        *reinterpret_cast<u16x8*>(qbuf + base + e) =
            *reinterpret_cast<const u16x8*>(otile + r * 136 + i * 64 + d);
      }
    } else if (mat == 1) {
      const size_t base = bh * 131072 + (size_t)(mloc >> 5) * 2048;
#pragma unroll
      for (int kk2 = 0; kk2 < 4; ++kk2) {
        const int e = kk2 * 2048 + tid * 8;
        const int r = kk2 * 32 + ((tid >> 1) & 31);
        const int d = ((tid >> 6) & 3) * 16 + (tid & 1) * 8;
        *reinterpret_cast<u16x8*>(kbuf + base + e) =
            *reinterpret_cast<const u16x8*>(otile + r * 136 + i * 64 + d);
      }
    } else {
      const size_t base = bh * 131072 + (size_t)(mloc >> 4) * 1024;
#pragma unroll
      for (int kk2 = 0; kk2 < 4; ++kk2) {
        const int e = kk2 * 2048 + tid * 8;
        const int d = ((tid >> 6) & 1) * 32 + ((tid >> 1) & 31);
        const int rb = (kk2 * 2 + (tid >> 7)) * 16;
        const int dl = (tid & 1) * 4;
        const unsigned short* srow = otile + (i * 64 + d) * 136 + rb + dl;
        ushort4 lo = *reinterpret_cast<const ushort4*>(srow);
        ushort4 hi4 = *reinterpret_cast<const ushort4*>(srow + 8);
        u16x8 w;
        w[0] = lo.x; w[1] = lo.y; w[2] = lo.z; w[3] = lo.w;
        w[4] = hi4.x; w[5] = hi4.y; w[6] = hi4.z; w[7] = hi4.w;
        *reinterpret_cast<u16x8*>(vtbuf + base + e) = w;
      }
    }
  }
}

// ---------------- flash attention: half-tile software pipeline ----------------
// grid 512 1-D XCD-affine; block 256 = 4 waves = 2 q-halves(64) x 2 kv-halves(1024).
// Per wave: 32 half-tiles of 32 kv, 2-stage pipelined:
//   body(h): issue K(h+2) loads | issue V(h) loads | QK(h+1) MFMAs (K loaded 1 body ago)
//            | softmax(h) VALU in MFMA shadow | pack(h) | PV(h) MFMAs.
// Softmax offset folded into MFMA C-init (cinit = -m2): no per-score sub, no zero-init.
// Row-sum cross-half shfl deferred to epilogue.
__global__ __launch_bounds__(256, 2) void k_attn(
    const unsigned short* __restrict__ qbuf, const unsigned short* __restrict__ kbuf,
    const unsigned short* __restrict__ vtbuf, const unsigned short* __restrict__ maskCb,
    const int* __restrict__ zflags, float* __restrict__ out) {
  __shared__ float obuf[2][64][68];
  __shared__ float mlbuf[4][2][32][2];
  const int tid = threadIdx.x, lane = tid & 63, wid = tid >> 6;
  const int lq = lane & 31, hi = lane >> 5;
  const int qh = wid & 1, kvh = wid >> 1;

  const int bid = blockIdx.x;
  const int xcd = bid & 7, loc = bid >> 3;
  const int bh = xcd * 4 + (loc >> 4);
  const int qblk = loc & 15;

  const int q0 = qblk * 128 + qh * 64;
  const int qgA = q0 + lq, qgB = q0 + 32 + lq;
  const size_t bhL = (size_t)bh * LSEQ;
  const unsigned short* kb = kbuf + (size_t)bh * 131072;
  const unsigned short* vb = vtbuf + (size_t)bh * 131072;
  const unsigned short* mbA = maskCb + ((size_t)hi * 2048 + qgA) * 16;
  const unsigned short* mbB = maskCb + ((size_t)hi * 2048 + qgB) * 16;
  const int lqh16 = lq * 16 + hi * 8;
  const int kv_beg = kvh * 1024;
  const int hk_base = kv_beg >> 5;          // K chunk index base (32-kv chunks)
  const int hv_base = kv_beg >> 4;          // V chunk index base (16-kv chunks)

  bf16x8 qfA[4], qfB[4];
#pragma unroll
  for (int c = 0; c < 4; ++c) {
    qfA[c] = *reinterpret_cast<const bf16x8*>(qbuf + (bhL + qgA) * 64 + c * 16 + hi * 8);
    qfB[c] = *reinterpret_cast<const bf16x8*>(qbuf + (bhL + qgB) * 64 + c * 16 + hi * 8);
  }

  f32x16 oA0 = {}, oA1 = {}, oB0 = {}, oB1 = {};
  float m2 = 2.0f, lA_loc = 0.f, lB_loc = 0.f;
  f32x16 cinit;
#pragma unroll
  for (int r = 0; r < 16; ++r) cinit[r] = -m2;

#define LOADK(KF, H) {                                                         \
    const unsigned short* kch = kb + (size_t)(hk_base + (H)) * 2048;           \
    KF[0] = *reinterpret_cast<const bf16x8*>(kch + lqh16);                     \
    KF[1] = *reinterpret_cast<const bf16x8*>(kch + 512 + lqh16);               \
    KF[2] = *reinterpret_cast<const bf16x8*>(kch + 1024 + lqh16);              \
    KF[3] = *reinterpret_cast<const bf16x8*>(kch + 1536 + lqh16);              \
  }

#define LOADV(VF, H) {                                                         \
    const unsigned short* vch = vb + (size_t)(hv_base + 2 * (H)) * 1024;       \
    VF[0] = *reinterpret_cast<const bf16x8*>(vch + lqh16);                     \
    VF[1] = *reinterpret_cast<const bf16x8*>(vch + 512 + lqh16);               \
    VF[2] = *reinterpret_cast<const bf16x8*>(vch + 1024 + lqh16);              \
    VF[3] = *reinterpret_cast<const bf16x8*>(vch + 1536 + lqh16);              \
  }

// QK for half H into SA,SB using K frags KF (C-init = cinit or mask-m2)
#define QKSTEP(SA, SB, KF, H) {                                                \
    const int kv32 = kv_beg + 32 * (H);                                        \
    const int zf = zflags[(kv32 >> 6) * 32 + (q0 >> 6)];                       \
    __builtin_amdgcn_s_setprio(1);                                             \
    if (zf) {                                                                  \
      SA = __builtin_amdgcn_mfma_f32_32x32x16_bf16(KF[0], qfA[0], cinit, 0, 0, 0); \
      SB = __builtin_amdgcn_mfma_f32_32x32x16_bf16(KF[0], qfB[0], cinit, 0, 0, 0); \
    } else {                                                                   \
      const size_t mo = (size_t)((kv32 >> 6) * 4 + ((kv32 >> 5) & 1) * 2) * 32768; \
      const unsigned short* mtA = mbA + mo;                                    \
      const unsigned short* mtB = mbB + mo;                                    \
      f32x16 cA = unpack16(*reinterpret_cast<const u16x8*>(mtA),               \
                           *reinterpret_cast<const u16x8*>(mtA + 8));          \
      f32x16 cB = unpack16(*reinterpret_cast<const u16x8*>(mtB),               \
                           *reinterpret_cast<const u16x8*>(mtB + 8));          \
      _Pragma("unroll")                                                        \
      for (int r = 0; r < 16; ++r) { cA[r] -= m2; cB[r] -= m2; }               \
      SA = __builtin_amdgcn_mfma_f32_32x32x16_bf16(KF[0], qfA[0], cA, 0, 0, 0); \
      SB = __builtin_amdgcn_mfma_f32_32x32x16_bf16(KF[0], qfB[0], cB, 0, 0, 0); \
    }                                                                          \
    _Pragma("unroll")                                                          \
    for (int c = 1; c < 4; ++c) {                                              \
      SA = __builtin_amdgcn_mfma_f32_32x32x16_bf16(KF[c], qfA[c], SA, 0, 0, 0); \
      SB = __builtin_amdgcn_mfma_f32_32x32x16_bf16(KF[c], qfB[c], SB, 0, 0, 0); \
    }                                                                          \
    __builtin_amdgcn_s_setprio(0);                                             \
  }

// softmax (exp2 direct, offset pre-folded) + overflow guard + pack + PV
#define SMAX_PV(SA, SB, VF) {                                                  \
    float a0 = 0.f, a1 = 0.f, b0 = 0.f, b1 = 0.f;                              \
    _Pragma("unroll")                                                          \
    for (int r = 0; r < 8; ++r) {                                              \
      SA[r] = exp2fast(SA[r]);         a0 += SA[r];                            \
      SA[r + 8] = exp2fast(SA[r + 8]); a1 += SA[r + 8];                        \
      SB[r] = exp2fast(SB[r]);         b0 += SB[r];                            \
      SB[r + 8] = exp2fast(SB[r + 8]); b1 += SB[r + 8];                        \
    }                                                                          \
    float rsA = a0 + a1, rsB = b0 + b1;                                        \
    if (__any(fmaxf(rsA, rsB) > 2048.f)) {                                     \
      const float cc = 0.000244140625f;                                        \
      _Pragma("unroll")                                                        \
      for (int r = 0; r < 16; ++r) {                                           \
        SA[r] *= cc; SB[r] *= cc;                                              \
        oA0[r] *= cc; oA1[r] *= cc; oB0[r] *= cc; oB1[r] *= cc;                \
      }                                                                        \
      rsA *= cc; rsB *= cc; lA_loc *= cc; lB_loc *= cc;                        \
      m2 += 12.f;                                                              \
      _Pragma("unroll")                                                        \
      for (int r = 0; r < 16; ++r) cinit[r] = -m2;                             \
    }                                                                          \
    lA_loc += rsA; lB_loc += rsB;                                              \
    bf16x8 pA0 = pack8(SA, 0), pB0 = pack8(SB, 0);                             \
    bf16x8 pA1 = pack8(SA, 8), pB1 = pack8(SB, 8);                             \
    __builtin_amdgcn_s_setprio(1);                                             \
    oA0 = __builtin_amdgcn_mfma_f32_32x32x16_bf16(VF[0], pA0, oA0, 0, 0, 0);   \
    oB0 = __builtin_amdgcn_mfma_f32_32x32x16_bf16(VF[0], pB0, oB0, 0, 0, 0);   \
    oA1 = __builtin_amdgcn_mfma_f32_32x32x16_bf16(VF[1], pA0, oA1, 0, 0, 0);   \
    oB1 = __builtin_amdgcn_mfma_f32_32x32x16_bf16(VF[1], pB0, oB1, 0, 0, 0);   \
    oA0 = __builtin_amdgcn_mfma_f32_32x32x16_bf16(VF[2], pA1, oA0, 0, 0, 0);   \
    oB0 = __builtin_amdgcn_mfma_f32_32x32x16_bf16(VF[2], pB1, oB0, 0, 0, 0);   \
    oA1 = __builtin_amdgcn_mfma_f32_32x32x16_bf16(VF[3], pA1, oA1, 0, 0, 0);   \
    oB1 = __builtin_amdgcn_mfma_f32_32x32x16_bf16(VF[3], pB1, oB1, 0, 0, 0);   \
    __builtin_amdgcn_s_setprio(0);                                             \
  }

  bf16x8 kf0[4], kf1[4], vf[4];
  f32x16 s0A, s0B, s1A, s1B;

  // prologue: K(0) -> QK half0 -> s0; issue K(1)
  LOADK(kf0, 0);
  QKSTEP(s0A, s0B, kf0, 0);
  LOADK(kf1, 1);

#pragma unroll 1
  for (int i = 0; i < 16; ++i) {
    const int h = 2 * i;
    // BODY A: process half h (s0); QK half h+1 via kf1; prefetch K(h+2)->kf0
    {
      const int hp = (h + 2 < 32) ? h + 2 : 31;
      LOADK(kf0, hp);
      LOADV(vf, h);
      QKSTEP(s1A, s1B, kf1, h + 1);
      SMAX_PV(s0A, s0B, vf);
    }
    // BODY B: process half h+1 (s1); QK half h+2 via kf0; prefetch K(h+3)->kf1
    {
      const int hp = (h + 3 < 32) ? h + 3 : 31;
      const int hq = (h + 2 < 32) ? h + 2 : 31;
      LOADK(kf1, hp);
      LOADV(vf, h + 1);
      QKSTEP(s0A, s0B, kf0, hq);
      SMAX_PV(s1A, s1B, vf);
    }
  }

  // complete lane-local row sums across the two lane-halves
  const float lA = lA_loc + __shfl_xor(lA_loc, 32, 64);
  const float lB = lB_loc + __shfl_xor(lB_loc, 32, 64);

  // ---- merge: exchange (m,l); kvh=0 stages scaled O in LDS; kvh=1 adds + stores ----
  if (lane < 32) {
    mlbuf[wid][0][lq][0] = m2; mlbuf[wid][0][lq][1] = lA;
    mlbuf[wid][1][lq][0] = m2; mlbuf[wid][1][lq][1] = lB;
  }
  __syncthreads();
  const int pw = wid ^ 2;
  const float mAp = mlbuf[pw][0][lq][0], lAp = mlbuf[pw][0][lq][1];
  const float mBp = mlbuf[pw][1][lq][0], lBp = mlbuf[pw][1][lq][1];
  const float msA = fmaxf(m2, mAp);
  const float fA = exp2fast(m2 - msA), fAp = exp2fast(mAp - msA);
  const float scaleA = fA / (lA * fA + lAp * fAp);
  const float msB = fmaxf(m2, mBp);
  const float fB = exp2fast(m2 - msB), fBp = exp2fast(mBp - msB);
  const float scaleB = fB / (lB * fB + lBp * fBp);

  if (kvh == 0) {
#pragma unroll
    for (int g = 0; g < 4; ++g) {
      const int d0 = 8 * g + 4 * hi;
      float4 wA0 = make_float4(oA0[4 * g] * scaleA, oA0[4 * g + 1] * scaleA,
                               oA0[4 * g + 2] * scaleA, oA0[4 * g + 3] * scaleA);
      float4 wA1 = make_float4(oA1[4 * g] * scaleA, oA1[4 * g + 1] * scaleA,
                               oA1[4 * g + 2] * scaleA, oA1[4 * g + 3] * scaleA);
      float4 wB0 = make_float4(oB0[4 * g] * scaleB, oB0[4 * g + 1] * scaleB,
                               oB0[4 * g + 2] * scaleB, oB0[4 * g + 3] * scaleB);
      float4 wB1 = make_float4(oB1[4 * g] * scaleB, oB1[4 * g + 1] * scaleB,
                               oB1[4 * g + 2] * scaleB, oB1[4 * g + 3] * scaleB);
      *reinterpret_cast<float4*>(&obuf[qh][lq][d0])           = wA0;
      *reinterpret_cast<float4*>(&obuf[qh][lq][d0 + 32])      = wA1;
      *reinterpret_cast<float4*>(&obuf[qh][32 + lq][d0])      = wB0;
      *reinterpret_cast<float4*>(&obuf[qh][32 + lq][d0 + 32]) = wB1;
    }
  }
  __syncthreads();
  if (kvh == 1) {
    const int b = bh >> 4, h = bh & 15;
    float* orowA = out + (size_t)(b * LSEQ + qgA) * DM + h * 64;
    float* orowB = out + (size_t)(b * LSEQ + qgB) * DM + h * 64;
#pragma unroll
    for (int g = 0; g < 4; ++g) {
      const int d0 = 8 * g + 4 * hi;
      float4 pA0 = *reinterpret_cast<const float4*>(&obuf[qh][lq][d0]);
      float4 pA1 = *reinterpret_cast<const float4*>(&obuf[qh][lq][d0 + 32]);
      float4 pB0 = *reinterpret_cast<const float4*>(&obuf[qh][32 + lq][d0]);
      float4 pB1 = *reinterpret_cast<const float4*>(&obuf[qh][32 + lq][d0 + 32]);
      float4 wA0 = make_float4(pA0.x + oA0[4 * g] * scaleA, pA0.y + oA0[4 * g + 1] * scaleA,
                               pA0.z + oA0[4 * g + 2] * scaleA, pA0.w + oA0[4 * g + 3] * scaleA);
      float4 wA1 = make_float4(pA1.x + oA1[4 * g] * scaleA, pA1.y + oA1[4 * g + 1] * scaleA,
                               pA1.z + oA1[4 * g + 2] * scaleA, pA1.w + oA1[4 * g + 3] * scaleA);
      float4 wB0 = make_float4(pB0.x + oB0[4 * g] * scaleB, pB0.y + oB0[4 * g + 1] * scaleB,
                               pB0.z + oB0[4 * g + 2] * scaleB, pB0.w + oB0[4 * g + 3] * scaleB);
      float4 wB1 = make_float4(pB1.x + oB1[4 * g] * scaleB, pB1.y + oB1[4 * g + 1] * scaleB,
                               pB1.z + oB1[4 * g + 2] * scaleB, pB1.w + oB1[4 * g + 3] * scaleB);
      *reinterpret_cast<float4*>(orowA + d0)      = wA0;
      *reinterpret_cast<float4*>(orowA + d0 + 32) = wA1;
      *reinterpret_cast<float4*>(orowB + d0)      = wB0;
      *reinterpret_cast<float4*>(orowB + d0 + 32) = wB1;
    }
  }
#undef LOADK
#undef LOADV
#undef QKSTEP
#undef SMAX_PV
}

extern "C" void kernel_launch(void* const* d_in, const int* in_sizes, int n_in,
                              void* d_out, int out_size, void* d_ws, size_t ws_size,
                              hipStream_t stream) {
  const float* data     = (const float*)d_in[0];
  const float* temporal = (const float*)d_in[1];
  const float* mask     = (const float*)d_in[2];
  const float* Wq       = (const float*)d_in[3];
  const float* bq       = (const float*)d_in[4];
  const float* Wk       = (const float*)d_in[5];
  const float* bk       = (const float*)d_in[6];
  const float* Wv       = (const float*)d_in[7];
  const float* bv       = (const float*)d_in[8];
  float* out = (float*)d_out;

  char* ws = (char*)d_ws;
  unsigned short* data_bf = (unsigned short*)(ws);                        // 8 MB (reused by maskCb)
  unsigned short* wt      = (unsigned short*)(ws + (size_t)8  * 1048576); // 6 MB (dead after gemm)
  unsigned short* qbuf    = (unsigned short*)(ws + (size_t)14 * 1048576); // 8 MB
  unsigned short* kbuf    = (unsigned short*)(ws + (size_t)22 * 1048576); // 8 MB
  unsigned short* vtbuf   = (unsigned short*)(ws + (size_t)30 * 1048576); // 8 MB
  unsigned short* maskCb  = data_bf;
  int* zflags             = (int*)wt;

  hipLaunchKernelGGL(k_convert_data, dim3(4096), dim3(256), 0, stream,
                     data, data_bf, (2 * LSEQ * DM) / 4);
  hipLaunchKernelGGL(k_transpose_w, dim3(16, 16, 3), dim3(256), 0, stream,
                     Wq, Wk, Wv, wt);
  hipLaunchKernelGGL(k_qkv_gemm, dim3(768), dim3(256), 0, stream,
                     data_bf, wt, bq, bk, bv, temporal, qbuf, kbuf, vtbuf);
  hipLaunchKernelGGL(k_maskC, dim3(32, 32), dim3(256), 0, stream,
                     mask, maskCb, zflags);
  hipLaunchKernelGGL(k_attn, dim3(512), dim3(256), 0, stream,
                     qbuf, kbuf, vtbuf, maskCb, zflags, out);
}